// Round 1
// baseline (189.595 us; speedup 1.0000x reference)
//
#include <hip/hip_runtime.h>

// SpikingJellyReservoirSNN: B=128, C=8, T=3000, R=1024
// v_{t+1} = 0.5*(v_t + I_t), spike iff v>=1, hard reset, count spikes.
// With the given init scales the network provably cannot spike (needs ~9-sigma
// events), so s @ W_rec^T == 0 for the whole run and the output is exactly 0.
// Strategy: a fast speculative kernel verifies "no spike ever" (conservative
// threshold 0.999 vs fp32 error ~1e-6) and writes zeros; an exact fallback
// kernel (early-exit on flag==0) handles the general case for correctness.

#define TT 3000
#define RDIM 1024
#define CDIM 8

__global__ void zero_flag_k(unsigned int* __restrict__ flag) {
    if (threadIdx.x == 0) flag[0] = 0u;
}

// ---------------------------------------------------------------------------
// Speculative pass: 512 blocks = 128 batches x 4 R-chunks, 256 threads,
// 1 neuron/thread. No inter-thread deps (assumes zero spikes; verifies it).
// ---------------------------------------------------------------------------
__global__ __launch_bounds__(256) void snn_spec(
    const float* __restrict__ x,    // [B, C, T]
    const float* __restrict__ Win,  // [R, C]
    const float* __restrict__ bin,  // [R]
    const float* __restrict__ brec, // [R]
    float* __restrict__ out,        // [B, R]
    unsigned int* __restrict__ flag)
{
    __shared__ __align__(16) float xbuf[1500 * CDIM]; // 48 KB: half of x[b]

    const int blk  = blockIdx.x;      // 0..511
    const int b    = blk >> 2;        // batch
    const int rblk = blk & 3;         // which 256-neuron chunk
    const int r    = rblk * 256 + threadIdx.x;

    // per-neuron weights + combined bias
    float w[CDIM];
#pragma unroll
    for (int c = 0; c < CDIM; ++c) w[c] = Win[r * CDIM + c];
    const float bias = bin[r] + brec[r];

    const float* xb = x + (size_t)b * (CDIM * TT);

    float v = 0.0f;
    float vmax = -1e30f;

    for (int half = 0; half < 2; ++half) {
        __syncthreads();
        // stage x[b][c][half*1500 + tt] -> xbuf[tt*8 + c]
        for (int idx = threadIdx.x; idx < 1500 * CDIM; idx += 256) {
            int c  = idx / 1500;
            int tt = idx - c * 1500;
            xbuf[tt * CDIM + c] = xb[c * TT + half * 1500 + tt];
        }
        __syncthreads();

#pragma unroll 4
        for (int tt = 0; tt < 1500; ++tt) {
            const float4* xr = reinterpret_cast<const float4*>(&xbuf[tt * CDIM]);
            float4 xa = xr[0];
            float4 xc = xr[1];
            // two partial chains for ILP; exact fp order is not load-bearing
            // (margins to threshold are ~0.2, fp32 error ~1e-6)
            float a0 = fmaf(xa.x, w[0], fmaf(xa.y, w[1], fmaf(xa.z, w[2], xa.w * w[3])));
            float a1 = fmaf(xc.x, w[4], fmaf(xc.y, w[5], fmaf(xc.z, w[6], xc.w * w[7])));
            float I = bias + (a0 + a1);
            v = v + (I - v) * 0.5f;
            vmax = fmaxf(vmax, v);
        }
    }

    if (vmax >= 0.999f) atomicOr(flag, 1u);
    out[(size_t)b * RDIM + r] = 0.0f;   // no spikes -> counts are exactly 0
}

// ---------------------------------------------------------------------------
// Exact fallback: 128 blocks (one per batch), 256 threads, 4 neurons/thread.
// Spike-driven sparse recurrent accumulation via ballot bitmasks in LDS.
// Early-exits when the speculative pass proved no spikes (the expected case).
// ---------------------------------------------------------------------------
__global__ __launch_bounds__(256) void snn_exact(
    const float* __restrict__ x,     // [B, C, T]
    const float* __restrict__ Win,   // [R, C]
    const float* __restrict__ bin,   // [R]
    const float* __restrict__ Wrec,  // [R, R]
    const float* __restrict__ brec,  // [R]
    float* __restrict__ out,         // [B, R]
    const unsigned int* __restrict__ flag)
{
    if (flag[0] == 0u) return;

    __shared__ unsigned long long wmask[2][16]; // 1024 spike bits, double-buffered

    const int b    = blockIdx.x;
    const int tid  = threadIdx.x;
    const int wid  = tid >> 6;
    const int lane = tid & 63;
    const int r0   = tid * 4;

    float w[4][CDIM], bias[4], v[4], cnt[4];
#pragma unroll
    for (int j = 0; j < 4; ++j) {
        const int r = r0 + j;
#pragma unroll
        for (int c = 0; c < CDIM; ++c) w[j][c] = Win[r * CDIM + c];
        bias[j] = bin[r] + brec[r];
        v[j] = 0.0f;
        cnt[j] = 0.0f;
    }

    if (tid < 16) wmask[0][tid] = 0ULL;
    __syncthreads();

    const float* xb = x + (size_t)b * (CDIM * TT);

    for (int t = 0; t < TT; ++t) {
        const int p = t & 1, q = p ^ 1;

        float xv[CDIM];
#pragma unroll
        for (int c = 0; c < CDIM; ++c) xv[c] = xb[c * TT + t];

        float I[4];
#pragma unroll
        for (int j = 0; j < 4; ++j) {
            float a = bias[j];
#pragma unroll
            for (int c = 0; c < CDIM; ++c) a = fmaf(xv[c], w[j][c], a);
            I[j] = a;
        }

        // sparse recurrent input from previous step's spikes
        for (int W = 0; W < 16; ++W) {
            unsigned long long m = wmask[p][W];
            while (m) {
                const int l = __ffsll(m) - 1;
                m &= m - 1;
                const int rp = ((W >> 2) << 8) + (l << 2) + (W & 3);
#pragma unroll
                for (int j = 0; j < 4; ++j)
                    I[j] += Wrec[(size_t)(r0 + j) * RDIM + rp];
            }
        }

        unsigned long long bm[4];
#pragma unroll
        for (int j = 0; j < 4; ++j) {
            float vv = v[j] + (I[j] - v[j]) * 0.5f;
            const bool s = (vv - 1.0f) >= 0.0f;
            cnt[j] += s ? 1.0f : 0.0f;
            v[j] = s ? 0.0f : vv;
            bm[j] = __ballot(s);
        }
        if (lane == 0) {
#pragma unroll
            for (int j = 0; j < 4; ++j) wmask[q][wid * 4 + j] = bm[j];
        }
        __syncthreads();
    }

#pragma unroll
    for (int j = 0; j < 4; ++j) out[(size_t)b * RDIM + r0 + j] = cnt[j];
}

extern "C" void kernel_launch(void* const* d_in, const int* in_sizes, int n_in,
                              void* d_out, int out_size, void* d_ws, size_t ws_size,
                              hipStream_t stream) {
    const float* x    = (const float*)d_in[0];
    const float* Win  = (const float*)d_in[1];
    const float* bin  = (const float*)d_in[2];
    const float* Wrec = (const float*)d_in[3];
    const float* brec = (const float*)d_in[4];
    float* out = (float*)d_out;
    unsigned int* flag = (unsigned int*)d_ws;

    hipLaunchKernelGGL(zero_flag_k, dim3(1), dim3(64), 0, stream, flag);
    hipLaunchKernelGGL(snn_spec, dim3(512), dim3(256), 0, stream,
                       x, Win, bin, brec, out, flag);
    hipLaunchKernelGGL(snn_exact, dim3(128), dim3(256), 0, stream,
                       x, Win, bin, Wrec, brec, out, flag);
}

// Round 2
// 32.153 us; speedup vs baseline: 5.8966x; 5.8966x over previous
//
#include <hip/hip_runtime.h>

// SpikingJellyReservoirSNN: B=128, C=8, T=3000, R=1024
// v_{t+1} = 0.5*(v_t + I_t), spike iff v>=1, hard reset, count.
//
// Key factorization (valid while no spikes occur): v is a LINEAR filter of I,
// so with y_t = 0.5*x_t + 0.5*y_{t-1} (per-channel EWMA, only B*C=1024 chains):
//     v[b,r,t] = w_r . y[b,t] + bias_r * (1 - 2^-(t+1))
// "Can anything spike?" is screened via Cauchy-Schwarz:
//     v <= ||w_r|| * ||y_bt|| + max(bias_r, 0)
// Only (b,t) with large ||y|| (~1e-4 fraction) get the exact 1024-neuron
// check. Any true crossing (or candidate-list overflow) sets a flag that
// routes to the exact full simulation, so the result is correct for ALL
// inputs; for this input the provable answer is all-zeros.

#define TT 3000
#define TPAD 3072
#define RDIM 1024
#define CDIM 8
#define BATCH 128
#define SEG 96
#define WARM 48
#define CAND_CAP 65536u
#define VTHR 0.999f

// d_ws layout (fp32 words):
//  [0] flag  [1] ncand  [2] wmax2  [3] bmax   [256 ..] y[B][C][TPAD]
//  [256 + B*C*TPAD ..] candidate list (u32, CAND_CAP entries)
#define Y_OFF 256
#define YWORDS (BATCH * CDIM * TPAD)
#define CAND_OFF (Y_OFF + YWORDS)
#define WS_WORDS_NEEDED (CAND_OFF + CAND_CAP)

// ---------------------------------------------------------------------------
__global__ void k0_init(const float* __restrict__ Win,
                        const float* __restrict__ bin,
                        const float* __restrict__ brec,
                        float* __restrict__ wsf)
{
    __shared__ float redw[256], redb[256];
    const int tid = threadIdx.x;
    float wmax2 = 0.0f, bmax = 0.0f;
#pragma unroll
    for (int j = 0; j < 4; ++j) {
        const int r = tid * 4 + j;
        float s = 0.0f;
#pragma unroll
        for (int c = 0; c < CDIM; ++c) {
            float w = Win[r * CDIM + c];
            s = fmaf(w, w, s);
        }
        wmax2 = fmaxf(wmax2, s);
        bmax = fmaxf(bmax, bin[r] + brec[r]);
    }
    redw[tid] = wmax2;
    redb[tid] = bmax;
    __syncthreads();
    for (int off = 128; off > 0; off >>= 1) {
        if (tid < off) {
            redw[tid] = fmaxf(redw[tid], redw[tid + off]);
            redb[tid] = fmaxf(redb[tid], redb[tid + off]);
        }
        __syncthreads();
    }
    if (tid == 0) {
        ((unsigned int*)wsf)[0] = 0u;          // flag
        ((unsigned int*)wsf)[1] = 0u;          // ncand
        wsf[2] = redw[0];                      // max ||w_r||^2
        wsf[3] = fmaxf(redb[0], 0.0f);         // max positive bias
    }
}

// ---------------------------------------------------------------------------
// EWMA of x per (b,c), segment-parallel with 48-step warmup (2^-48 error).
// grid = B blocks, 256 threads = 8 channels x 32 segments of 96 steps.
__global__ __launch_bounds__(256) void k1_ewma(
    const float* __restrict__ x,   // [B, C, T]
    float* __restrict__ wsf)
{
    const int b = blockIdx.x;
    const int tid = threadIdx.x;
    const int c = tid >> 5;
    const int s = tid & 31;
    const int tstart = s * SEG;

    const float* xc = x + ((size_t)b * CDIM + c) * TT;
    float* yc = wsf + Y_OFF + ((size_t)b * CDIM + c) * TPAD;

    float y = 0.0f;
    if (s > 0) {
        const int w0 = tstart - WARM;            // multiple of 16 bytes
#pragma unroll
        for (int k = 0; k < WARM / 4; ++k) {
            const float4 xv = *reinterpret_cast<const float4*>(xc + w0 + 4 * k);
            y = 0.5f * (xv.x + y);
            y = 0.5f * (xv.y + y);
            y = 0.5f * (xv.z + y);
            y = 0.5f * (xv.w + y);
        }
    }
#pragma unroll 4
    for (int k = 0; k < SEG / 4; ++k) {
        const int t4 = tstart + 4 * k;
        if (t4 >= TT) break;                     // only last segment clips
        const float4 xv = *reinterpret_cast<const float4*>(xc + t4);
        float4 yv;
        y = 0.5f * (xv.x + y); yv.x = y;
        y = 0.5f * (xv.y + y); yv.y = y;
        y = 0.5f * (xv.z + y); yv.z = y;
        y = 0.5f * (xv.w + y); yv.w = y;
        *reinterpret_cast<float4*>(yc + t4) = yv;
    }
}

// ---------------------------------------------------------------------------
// Screen: (b,t) is a candidate iff wmax*||y|| + bmax >= VTHR.
// grid = B*12 blocks x 256 (12*256 = 3072 >= T).
__global__ __launch_bounds__(256) void k2_screen(float* __restrict__ wsf)
{
    const int b = blockIdx.x / 12;
    const int t = (blockIdx.x % 12) * 256 + threadIdx.x;
    if (t >= TT) return;

    const float wmax2 = wsf[2];
    const float bmax  = wsf[3];
    const float* yb = wsf + Y_OFF + (size_t)b * CDIM * TPAD;

    float s2 = 0.0f;
#pragma unroll
    for (int c = 0; c < CDIM; ++c) {
        const float yv = yb[(size_t)c * TPAD + t];
        s2 = fmaf(yv, yv, s2);
    }

    const float rhs = VTHR - bmax;
    const bool cand = (rhs <= 0.0f) || (s2 * wmax2 >= rhs * rhs);
    if (cand) {
        unsigned int* ncand = (unsigned int*)wsf + 1;
        unsigned int* list  = (unsigned int*)wsf + CAND_OFF;
        const unsigned int idx = atomicAdd(ncand, 1u);
        if (idx < CAND_CAP) list[idx] = ((unsigned int)b << 16) | (unsigned int)t;
        else atomicOr((unsigned int*)wsf, 1u);   // overflow -> conservative flag
    }
}

// ---------------------------------------------------------------------------
// Exact per-neuron check of each candidate (b,t).
__global__ __launch_bounds__(256) void k3_cand(
    const float* __restrict__ Win,
    const float* __restrict__ bin,
    const float* __restrict__ brec,
    float* __restrict__ wsf)
{
    const unsigned int* ncand_p = (const unsigned int*)wsf + 1;
    const unsigned int* list    = (const unsigned int*)wsf + CAND_OFF;
    unsigned int n = *ncand_p;
    if (n > CAND_CAP) n = CAND_CAP;

    const int tid = threadIdx.x;
    bool hit = false;

    for (unsigned int ci = blockIdx.x; ci < n; ci += gridDim.x) {
        const unsigned int e = list[ci];
        const int b = (int)(e >> 16);
        const int t = (int)(e & 0xffffu);

        float yv[CDIM];
        const float* yb = wsf + Y_OFF + (size_t)b * CDIM * TPAD;
#pragma unroll
        for (int c = 0; c < CDIM; ++c) yv[c] = yb[(size_t)c * TPAD + t];

        const float factor = 1.0f - exp2f(-(float)(t + 1));
#pragma unroll
        for (int j = 0; j < 4; ++j) {
            const int r = tid * 4 + j;
            float a = 0.0f;
#pragma unroll
            for (int c = 0; c < CDIM; ++c) a = fmaf(Win[r * CDIM + c], yv[c], a);
            const float v = a + (bin[r] + brec[r]) * factor;
            hit = hit || (v >= VTHR);
        }
    }
    if (hit) atomicOr((unsigned int*)wsf, 1u);
}

// ---------------------------------------------------------------------------
__global__ void k4_zero_out(float* __restrict__ out)
{
    out[blockIdx.x * 256 + threadIdx.x] = 0.0f;
}

// ---------------------------------------------------------------------------
// Legacy speculative kernel (ws-too-small fallback path only).
__global__ __launch_bounds__(256) void snn_spec(
    const float* __restrict__ x, const float* __restrict__ Win,
    const float* __restrict__ bin, const float* __restrict__ brec,
    float* __restrict__ out, unsigned int* __restrict__ flag)
{
    __shared__ __align__(16) float xbuf[1500 * CDIM];
    const int blk = blockIdx.x;
    const int b = blk >> 2;
    const int r = (blk & 3) * 256 + threadIdx.x;

    float w[CDIM];
#pragma unroll
    for (int c = 0; c < CDIM; ++c) w[c] = Win[r * CDIM + c];
    const float bias = bin[r] + brec[r];
    const float* xb = x + (size_t)b * (CDIM * TT);

    float v = 0.0f, vmax = -1e30f;
    for (int half = 0; half < 2; ++half) {
        __syncthreads();
        for (int idx = threadIdx.x; idx < 1500 * CDIM; idx += 256) {
            int c = idx / 1500;
            int tt = idx - c * 1500;
            xbuf[tt * CDIM + c] = xb[c * TT + half * 1500 + tt];
        }
        __syncthreads();
#pragma unroll 4
        for (int tt = 0; tt < 1500; ++tt) {
            const float4* xr = reinterpret_cast<const float4*>(&xbuf[tt * CDIM]);
            float4 xa = xr[0], xc = xr[1];
            float a0 = fmaf(xa.x, w[0], fmaf(xa.y, w[1], fmaf(xa.z, w[2], xa.w * w[3])));
            float a1 = fmaf(xc.x, w[4], fmaf(xc.y, w[5], fmaf(xc.z, w[6], xc.w * w[7])));
            float I = bias + (a0 + a1);
            v = v + (I - v) * 0.5f;
            vmax = fmaxf(vmax, v);
        }
    }
    if (vmax >= VTHR) atomicOr(flag, 1u);
    out[(size_t)b * RDIM + r] = 0.0f;
}

__global__ void zero_flag_k(unsigned int* __restrict__ flag) {
    if (threadIdx.x == 0) flag[0] = 0u;
}

// ---------------------------------------------------------------------------
// Exact fallback: full synchronized sim, early-exits when flag==0.
__global__ __launch_bounds__(256) void snn_exact(
    const float* __restrict__ x, const float* __restrict__ Win,
    const float* __restrict__ bin, const float* __restrict__ Wrec,
    const float* __restrict__ brec, float* __restrict__ out,
    const unsigned int* __restrict__ flag)
{
    if (flag[0] == 0u) return;

    __shared__ unsigned long long wmask[2][16];
    const int b = blockIdx.x;
    const int tid = threadIdx.x;
    const int wid = tid >> 6;
    const int lane = tid & 63;
    const int r0 = tid * 4;

    float w[4][CDIM], bias[4], v[4], cnt[4];
#pragma unroll
    for (int j = 0; j < 4; ++j) {
        const int r = r0 + j;
#pragma unroll
        for (int c = 0; c < CDIM; ++c) w[j][c] = Win[r * CDIM + c];
        bias[j] = bin[r] + brec[r];
        v[j] = 0.0f;
        cnt[j] = 0.0f;
    }
    if (tid < 16) wmask[0][tid] = 0ULL;
    __syncthreads();

    const float* xb = x + (size_t)b * (CDIM * TT);

    for (int t = 0; t < TT; ++t) {
        const int p = t & 1, q = p ^ 1;
        float xv[CDIM];
#pragma unroll
        for (int c = 0; c < CDIM; ++c) xv[c] = xb[c * TT + t];

        float I[4];
#pragma unroll
        for (int j = 0; j < 4; ++j) {
            float a = bias[j];
#pragma unroll
            for (int c = 0; c < CDIM; ++c) a = fmaf(xv[c], w[j][c], a);
            I[j] = a;
        }
        for (int W = 0; W < 16; ++W) {
            unsigned long long m = wmask[p][W];
            while (m) {
                const int l = __ffsll(m) - 1;
                m &= m - 1;
                const int rp = ((W >> 2) << 8) + (l << 2) + (W & 3);
#pragma unroll
                for (int j = 0; j < 4; ++j)
                    I[j] += Wrec[(size_t)(r0 + j) * RDIM + rp];
            }
        }
        unsigned long long bm[4];
#pragma unroll
        for (int j = 0; j < 4; ++j) {
            float vv = v[j] + (I[j] - v[j]) * 0.5f;
            const bool sp = (vv - 1.0f) >= 0.0f;
            cnt[j] += sp ? 1.0f : 0.0f;
            v[j] = sp ? 0.0f : vv;
            bm[j] = __ballot(sp);
        }
        if (lane == 0) {
#pragma unroll
            for (int j = 0; j < 4; ++j) wmask[q][wid * 4 + j] = bm[j];
        }
        __syncthreads();
    }
#pragma unroll
    for (int j = 0; j < 4; ++j) out[(size_t)b * RDIM + r0 + j] = cnt[j];
}

// ---------------------------------------------------------------------------
extern "C" void kernel_launch(void* const* d_in, const int* in_sizes, int n_in,
                              void* d_out, int out_size, void* d_ws, size_t ws_size,
                              hipStream_t stream) {
    const float* x    = (const float*)d_in[0];
    const float* Win  = (const float*)d_in[1];
    const float* bin  = (const float*)d_in[2];
    const float* Wrec = (const float*)d_in[3];
    const float* brec = (const float*)d_in[4];
    float* out = (float*)d_out;
    float* wsf = (float*)d_ws;

    if (ws_size >= (size_t)WS_WORDS_NEEDED * 4u) {
        hipLaunchKernelGGL(k0_init, dim3(1), dim3(256), 0, stream, Win, bin, brec, wsf);
        hipLaunchKernelGGL(k1_ewma, dim3(BATCH), dim3(256), 0, stream, x, wsf);
        hipLaunchKernelGGL(k2_screen, dim3(BATCH * 12), dim3(256), 0, stream, wsf);
        hipLaunchKernelGGL(k3_cand, dim3(256), dim3(256), 0, stream, Win, bin, brec, wsf);
        hipLaunchKernelGGL(k4_zero_out, dim3(BATCH * RDIM / 256), dim3(256), 0, stream, out);
        hipLaunchKernelGGL(snn_exact, dim3(BATCH), dim3(256), 0, stream,
                           x, Win, bin, Wrec, brec, out, (const unsigned int*)wsf);
    } else {
        unsigned int* flag = (unsigned int*)d_ws;
        hipLaunchKernelGGL(zero_flag_k, dim3(1), dim3(64), 0, stream, flag);
        hipLaunchKernelGGL(snn_spec, dim3(512), dim3(256), 0, stream,
                           x, Win, bin, brec, out, flag);
        hipLaunchKernelGGL(snn_exact, dim3(BATCH), dim3(256), 0, stream,
                           x, Win, bin, Wrec, brec, out, flag);
    }
}

// Round 3
// 21.781 us; speedup vs baseline: 8.7046x; 1.4762x over previous
//
#include <hip/hip_runtime.h>

// SpikingJellyReservoirSNN: B=128, C=8, T=3000, R=1024
// v_{t+1} = 0.5*(v_t + I_t), spike iff v>=1, hard reset, count.
//
// Factorization (exact until the first spike): v is a linear filter of I, so
// with per-channel EWMA y_t = 0.5*x_t + 0.5*y_{t-1} (B*C = 1024 chains):
//     v[b,r,t] = w_r . y[b,t] + bias_r * (1 - 2^-(t+1))
// Screen via Cauchy-Schwarz: v <= ||w_r||*||y_bt|| + max(bias_r, 0).
// Only (b,t) passing the screen (~1e-4 fraction) get the exact 1024-neuron
// check; any true crossing (or any overflow) routes to the exact full
// simulation, so the result is correct for ALL inputs. For this input the
// provable answer is all-zeros (first crossing would need a ~9-sigma event).
//
// This revision: 3 dependent launches (was 6), no y materialization, no
// pre-zeroing kernel (all ws control words are unconditionally written by
// their owning block; block-local LDS candidate counters).

#define TT 3000
#define RDIM 1024
#define CDIM 8
#define BATCH 128
#define SEG 32
#define WARM 32          // warmup steps; truncation error 2^-32 vs 1e-3 margin
#define NSEG 94          // ceil(3000/32); segment 93 has 24 steps
#define CAP_BLK 256
#define ENT_W 16         // words per candidate entry (64B aligned)
#define VTHR 0.999f      // conservative vs true 1.0 (fp error ~1e-6)

// ws layout (32-bit words):
//  [0..127]    per-batch flag from k1 (overflow / trivially-spiking)
//  [128..255]  per-batch candidate count from k1
//  [256..383]  per-block hit flag from k3
//  [512 + b*CAP_BLK*ENT_W + i*ENT_W ...]  entry: [0]=(b<<16)|t, [1..8]=y[8]
#define FLG1_OFF 0
#define CNT_OFF 128
#define FLG3_OFF 256
#define ENT_OFF 512
#define WS_WORDS_NEEDED (ENT_OFF + BATCH * CAP_BLK * ENT_W)

// ---------------------------------------------------------------------------
// k1: per-block (one batch): compute wmax2/bmax from weights, then 94
// segment-threads run 8 register-resident channel EWMAs + inline screen.
// ---------------------------------------------------------------------------
__global__ __launch_bounds__(128) void k1_fused(
    const float* __restrict__ x,    // [B, C, T]
    const float* __restrict__ Win,  // [R, C]
    const float* __restrict__ bin,  // [R]
    const float* __restrict__ brec, // [R]
    float* __restrict__ wsf)
{
    const int b   = blockIdx.x;
    const int tid = threadIdx.x;

    __shared__ float rw[128], rb[128];
    __shared__ int cnt, ovf;

    // ---- phase 1: wmax2 = max_r ||w_r||^2, bmax = max_r (bin+brec) ----
    float wm = 0.0f, bm = -1e30f;
    for (int r = tid; r < RDIM; r += 128) {
        const float4* wr = reinterpret_cast<const float4*>(Win + (size_t)r * CDIM);
        const float4 w0 = wr[0], w1 = wr[1];
        float s = w0.x * w0.x + w0.y * w0.y + w0.z * w0.z + w0.w * w0.w +
                  w1.x * w1.x + w1.y * w1.y + w1.z * w1.z + w1.w * w1.w;
        wm = fmaxf(wm, s);
        bm = fmaxf(bm, bin[r] + brec[r]);
    }
    rw[tid] = wm;
    rb[tid] = bm;
    if (tid == 0) { cnt = 0; ovf = 0; }
    __syncthreads();
    for (int off = 64; off > 0; off >>= 1) {
        if (tid < off) {
            rw[tid] = fmaxf(rw[tid], rw[tid + off]);
            rb[tid] = fmaxf(rb[tid], rb[tid + off]);
        }
        __syncthreads();
    }
    const float wmax2   = rw[0];
    const float bmax    = fmaxf(rb[0], 0.0f);
    const float rhs     = VTHR - bmax;
    const bool  trivial = (rhs <= 0.0f);     // bias alone can cross -> full sim
    const float rhs2    = rhs * rhs;

    // ---- phase 2: EWMA + screen, one segment per thread ----
    if (tid < NSEG && !trivial) {
        const int tstart = tid * SEG;
        const float* xb = x + (size_t)b * CDIM * TT;

        float y[CDIM];
#pragma unroll
        for (int c = 0; c < CDIM; ++c) y[c] = 0.0f;

        if (tid > 0) {                       // warmup (2^-32 truncation)
            const int tw = tstart - WARM;
#pragma unroll
            for (int k = 0; k < WARM / 4; ++k) {
                float4 xv[CDIM];
#pragma unroll
                for (int c = 0; c < CDIM; ++c)
                    xv[c] = *reinterpret_cast<const float4*>(xb + (size_t)c * TT + tw + 4 * k);
#pragma unroll
                for (int j = 0; j < 4; ++j) {
#pragma unroll
                    for (int c = 0; c < CDIM; ++c) {
                        const float xs = (j == 0) ? xv[c].x : (j == 1) ? xv[c].y
                                       : (j == 2) ? xv[c].z : xv[c].w;
                        y[c] = 0.5f * (xs + y[c]);
                    }
                }
            }
        }

        for (int k = 0; k < SEG / 4; ++k) {
            const int t4 = tstart + 4 * k;
            if (t4 >= TT) break;             // only segment 93 clips (24 steps)
            float4 xv[CDIM];
#pragma unroll
            for (int c = 0; c < CDIM; ++c)
                xv[c] = *reinterpret_cast<const float4*>(xb + (size_t)c * TT + t4);
#pragma unroll
            for (int j = 0; j < 4; ++j) {
                float s2 = 0.0f;
#pragma unroll
                for (int c = 0; c < CDIM; ++c) {
                    const float xs = (j == 0) ? xv[c].x : (j == 1) ? xv[c].y
                                   : (j == 2) ? xv[c].z : xv[c].w;
                    y[c] = 0.5f * (xs + y[c]);
                    s2 = fmaf(y[c], y[c], s2);
                }
                if (s2 * wmax2 >= rhs2) {    // Cauchy-Schwarz screen
                    const int i = atomicAdd(&cnt, 1);
                    if (i < CAP_BLK) {
                        float* e = wsf + ENT_OFF + ((size_t)b * CAP_BLK + i) * ENT_W;
                        ((unsigned int*)e)[0] =
                            ((unsigned int)b << 16) | (unsigned int)(t4 + j);
#pragma unroll
                        for (int c = 0; c < CDIM; ++c) e[1 + c] = y[c];
                    } else {
                        ovf = 1;             // benign race: all writers store 1
                    }
                }
            }
        }
    }
    __syncthreads();
    if (tid == 0) {
        ((unsigned int*)wsf)[FLG1_OFF + b] = (trivial || ovf) ? 1u : 0u;
        ((unsigned int*)wsf)[CNT_OFF + b]  = (unsigned int)(cnt < CAP_BLK ? cnt : CAP_BLK);
    }
}

// ---------------------------------------------------------------------------
// k3: zero out + exact per-neuron check of this batch's candidates.
// Unconditionally writes its hit-flag word (no pre-zeroing needed).
// ---------------------------------------------------------------------------
__global__ __launch_bounds__(256) void k3_check(
    const float* __restrict__ Win,
    const float* __restrict__ bin,
    const float* __restrict__ brec,
    float* __restrict__ out,        // [B, R]
    float* __restrict__ wsf)
{
    const int blk = blockIdx.x;     // = batch
    const int tid = threadIdx.x;

    // zero this batch's output row (1024 floats = 256 x float4)
    float4* ob = reinterpret_cast<float4*>(out + (size_t)blk * RDIM);
    ob[tid] = make_float4(0.0f, 0.0f, 0.0f, 0.0f);

    const unsigned int n = ((const unsigned int*)wsf)[CNT_OFF + blk];
    bool hit = false;

    for (unsigned int i = 0; i < n; ++i) {
        const float* e = wsf + ENT_OFF + ((size_t)blk * CAP_BLK + i) * ENT_W;
        const int t = (int)(((const unsigned int*)e)[0] & 0xffffu);
        float yv[CDIM];
#pragma unroll
        for (int c = 0; c < CDIM; ++c) yv[c] = e[1 + c];
        const float factor = 1.0f - exp2f(-(float)(t + 1));
#pragma unroll
        for (int j = 0; j < 4; ++j) {
            const int r = tid * 4 + j;
            const float4* wr = reinterpret_cast<const float4*>(Win + (size_t)r * CDIM);
            const float4 w0 = wr[0], w1 = wr[1];
            const float a = w0.x * yv[0] + w0.y * yv[1] + w0.z * yv[2] + w0.w * yv[3] +
                            w1.x * yv[4] + w1.y * yv[5] + w1.z * yv[6] + w1.w * yv[7];
            const float v = a + (bin[r] + brec[r]) * factor;
            hit = hit || (v >= VTHR);
        }
    }

    __shared__ int h;
    if (tid == 0) h = 0;
    __syncthreads();
    if (__ballot(hit) && (tid & 63) == 0) atomicOr(&h, 1);
    __syncthreads();
    if (tid == 0) ((unsigned int*)wsf)[FLG3_OFF + blk] = (unsigned int)h;
}

// ---------------------------------------------------------------------------
// Exact fallback: full synchronized sim; early-exits when no flag is set.
// ---------------------------------------------------------------------------
__global__ __launch_bounds__(256) void snn_exact(
    const float* __restrict__ x, const float* __restrict__ Win,
    const float* __restrict__ bin, const float* __restrict__ Wrec,
    const float* __restrict__ brec, float* __restrict__ out,
    const unsigned int* __restrict__ wsu)
{
    const int tid = threadIdx.x;

    // OR all 256 flag words (k1: [0..127], k3: [256..383])
    unsigned int m = 0;
    if (tid < BATCH) m = wsu[FLG1_OFF + tid] | wsu[FLG3_OFF + tid];
    __shared__ unsigned int f;
    if (tid == 0) f = 0u;
    __syncthreads();
    if (m) atomicOr(&f, 1u);
    __syncthreads();
    if (f == 0u) return;

    __shared__ unsigned long long wmask[2][16];
    const int b    = blockIdx.x;
    const int wid  = tid >> 6;
    const int lane = tid & 63;
    const int r0   = tid * 4;

    float w[4][CDIM], bias[4], v[4], cntv[4];
#pragma unroll
    for (int j = 0; j < 4; ++j) {
        const int r = r0 + j;
#pragma unroll
        for (int c = 0; c < CDIM; ++c) w[j][c] = Win[r * CDIM + c];
        bias[j] = bin[r] + brec[r];
        v[j] = 0.0f;
        cntv[j] = 0.0f;
    }
    if (tid < 16) wmask[0][tid] = 0ULL;
    __syncthreads();

    const float* xb = x + (size_t)b * (CDIM * TT);

    for (int t = 0; t < TT; ++t) {
        const int p = t & 1, q = p ^ 1;
        float xv[CDIM];
#pragma unroll
        for (int c = 0; c < CDIM; ++c) xv[c] = xb[c * TT + t];

        float I[4];
#pragma unroll
        for (int j = 0; j < 4; ++j) {
            float a = bias[j];
#pragma unroll
            for (int c = 0; c < CDIM; ++c) a = fmaf(xv[c], w[j][c], a);
            I[j] = a;
        }
        for (int W = 0; W < 16; ++W) {
            unsigned long long mm = wmask[p][W];
            while (mm) {
                const int l = __ffsll(mm) - 1;
                mm &= mm - 1;
                const int rp = ((W >> 2) << 8) + (l << 2) + (W & 3);
#pragma unroll
                for (int j = 0; j < 4; ++j)
                    I[j] += Wrec[(size_t)(r0 + j) * RDIM + rp];
            }
        }
        unsigned long long bmv[4];
#pragma unroll
        for (int j = 0; j < 4; ++j) {
            float vv = v[j] + (I[j] - v[j]) * 0.5f;
            const bool sp = (vv - 1.0f) >= 0.0f;
            cntv[j] += sp ? 1.0f : 0.0f;
            v[j] = sp ? 0.0f : vv;
            bmv[j] = __ballot(sp);
        }
        if (lane == 0) {
#pragma unroll
            for (int j = 0; j < 4; ++j) wmask[q][wid * 4 + j] = bmv[j];
        }
        __syncthreads();
    }
#pragma unroll
    for (int j = 0; j < 4; ++j) out[(size_t)b * RDIM + r0 + j] = cntv[j];
}

// ---------------------------------------------------------------------------
// Legacy path (only if ws is too small): brute-force speculative check.
// ---------------------------------------------------------------------------
__global__ void zero_flag_k(unsigned int* __restrict__ ws) {
    const int i = blockIdx.x * blockDim.x + threadIdx.x;
    if (i < 384) ws[i] = 0u;
}

__global__ __launch_bounds__(256) void snn_spec(
    const float* __restrict__ x, const float* __restrict__ Win,
    const float* __restrict__ bin, const float* __restrict__ brec,
    float* __restrict__ out, unsigned int* __restrict__ flag)
{
    __shared__ __align__(16) float xbuf[1500 * CDIM];
    const int blk = blockIdx.x;
    const int b = blk >> 2;
    const int r = (blk & 3) * 256 + threadIdx.x;

    float w[CDIM];
#pragma unroll
    for (int c = 0; c < CDIM; ++c) w[c] = Win[r * CDIM + c];
    const float bias = bin[r] + brec[r];
    const float* xb = x + (size_t)b * (CDIM * TT);

    float v = 0.0f, vmax = -1e30f;
    for (int half = 0; half < 2; ++half) {
        __syncthreads();
        for (int idx = threadIdx.x; idx < 1500 * CDIM; idx += 256) {
            int c = idx / 1500;
            int tt = idx - c * 1500;
            xbuf[tt * CDIM + c] = xb[c * TT + half * 1500 + tt];
        }
        __syncthreads();
#pragma unroll 4
        for (int tt = 0; tt < 1500; ++tt) {
            const float4* xr = reinterpret_cast<const float4*>(&xbuf[tt * CDIM]);
            float4 xa = xr[0], xc = xr[1];
            float a0 = fmaf(xa.x, w[0], fmaf(xa.y, w[1], fmaf(xa.z, w[2], xa.w * w[3])));
            float a1 = fmaf(xc.x, w[4], fmaf(xc.y, w[5], fmaf(xc.z, w[6], xc.w * w[7])));
            float I = bias + (a0 + a1);
            v = v + (I - v) * 0.5f;
            vmax = fmaxf(vmax, v);
        }
    }
    if (vmax >= VTHR) atomicOr(flag, 1u);
    out[(size_t)b * RDIM + r] = 0.0f;
}

// ---------------------------------------------------------------------------
extern "C" void kernel_launch(void* const* d_in, const int* in_sizes, int n_in,
                              void* d_out, int out_size, void* d_ws, size_t ws_size,
                              hipStream_t stream) {
    const float* x    = (const float*)d_in[0];
    const float* Win  = (const float*)d_in[1];
    const float* bin  = (const float*)d_in[2];
    const float* Wrec = (const float*)d_in[3];
    const float* brec = (const float*)d_in[4];
    float* out = (float*)d_out;
    float* wsf = (float*)d_ws;

    if (ws_size >= (size_t)WS_WORDS_NEEDED * 4u) {
        hipLaunchKernelGGL(k1_fused, dim3(BATCH), dim3(128), 0, stream,
                           x, Win, bin, brec, wsf);
        hipLaunchKernelGGL(k3_check, dim3(BATCH), dim3(256), 0, stream,
                           Win, bin, brec, out, wsf);
        hipLaunchKernelGGL(snn_exact, dim3(BATCH), dim3(256), 0, stream,
                           x, Win, bin, Wrec, brec, out, (const unsigned int*)wsf);
    } else {
        unsigned int* flag = (unsigned int*)d_ws;
        hipLaunchKernelGGL(zero_flag_k, dim3(2), dim3(256), 0, stream, flag);
        hipLaunchKernelGGL(snn_spec, dim3(512), dim3(256), 0, stream,
                           x, Win, bin, brec, out, flag);
        hipLaunchKernelGGL(snn_exact, dim3(BATCH), dim3(256), 0, stream,
                           x, Win, bin, Wrec, brec, out, flag);
    }
}

// Round 4
// 17.887 us; speedup vs baseline: 10.5993x; 1.2177x over previous
//
#include <hip/hip_runtime.h>

// SpikingJellyReservoirSNN: B=128, C=8, T=3000, R=1024
// v_{t+1} = 0.5*(v_t + I_t), spike iff v>=1, hard reset, count.
//
// Factorization (exact until the first spike): v is a linear filter of I, so
// with per-channel EWMA y_t = 0.5*x_t + 0.5*y_{t-1} (C=8 chains per batch):
//     v[b,r,t] = w_r . y[b,t] + bias_r * (1 - 2^-(t+1))
// Screen via Cauchy-Schwarz: v <= ||w_r||*||y_bt|| + max(bias_r, 0).
// (b,t) passing the screen (~1e-4 fraction) get an exact 1024-neuron check;
// if any neuron could truly cross (or the screen is inconclusive: trivial
// bias / candidate overflow), the block falls through to the exact full
// simulation of ITS OWN batch — batches are independent (recurrence is
// batch-diagonal), so one block per batch needs no cross-block data at all.
// => ONE kernel launch, no workspace. Correct for ALL inputs; for this input
// the provable answer is all-zeros (a crossing would need a ~9-sigma event).

#define TT 3000
#define RDIM 1024
#define CDIM 8
#define BATCH 128
#define SEG 24          // timesteps per screen-thread; 125*24 = 3000 exactly
#define NSEG 125
#define WARM 32         // warmup steps (2^-32 truncation vs 1e-3 margin);
                        // segments starting < WARM warm from t=0 (exact)
#define CAP 128         // LDS candidate capacity; overflow -> full sim
#define VTHR 0.999f     // conservative vs true 1.0 (fp error ~1e-6)

__global__ __launch_bounds__(256) void snn_all(
    const float* __restrict__ x,     // [B, C, T]
    const float* __restrict__ Win,   // [R, C]
    const float* __restrict__ bin,   // [R]
    const float* __restrict__ Wrec,  // [R, R]
    const float* __restrict__ brec,  // [R]
    float* __restrict__ out)         // [B, R]
{
    const int b   = blockIdx.x;
    const int tid = threadIdx.x;

    __shared__ float rw[256], rb[256];
    __shared__ float cy[CAP][CDIM];
    __shared__ int   ct[CAP];
    __shared__ int   cnt, ovf, hit;
    __shared__ unsigned long long wmask[2][16];

    // ---- phase 1: wmax2 = max_r ||w_r||^2, bmax = max_r max(bias_r, 0) ----
    float wm = 0.0f, bm = -1e30f;
#pragma unroll
    for (int k = 0; k < 4; ++k) {
        const int r = tid + k * 256;
        const float4* wr = reinterpret_cast<const float4*>(Win + (size_t)r * CDIM);
        const float4 w0 = wr[0], w1 = wr[1];
        const float s = w0.x * w0.x + w0.y * w0.y + w0.z * w0.z + w0.w * w0.w +
                        w1.x * w1.x + w1.y * w1.y + w1.z * w1.z + w1.w * w1.w;
        wm = fmaxf(wm, s);
        bm = fmaxf(bm, bin[r] + brec[r]);
    }
    rw[tid] = wm;
    rb[tid] = bm;
    if (tid == 0) { cnt = 0; ovf = 0; hit = 0; }
    __syncthreads();
    for (int off = 128; off > 0; off >>= 1) {
        if (tid < off) {
            rw[tid] = fmaxf(rw[tid], rw[tid + off]);
            rb[tid] = fmaxf(rb[tid], rb[tid + off]);
        }
        __syncthreads();
    }
    const float wmax2   = rw[0];
    const float bmax    = fmaxf(rb[0], 0.0f);
    const float rhs     = VTHR - bmax;
    const bool  trivial = (rhs <= 0.0f);   // bias alone could cross
    const float rhs2    = rhs * rhs;

    // ---- phase 2: segment-parallel EWMA + inline Cauchy-Schwarz screen ----
    if (!trivial && tid < NSEG) {
        const int tstart = tid * SEG;
        const float* xb = x + (size_t)b * CDIM * TT;

        float y[CDIM];
#pragma unroll
        for (int c = 0; c < CDIM; ++c) y[c] = 0.0f;

        const int w0t = tstart - WARM;     // may be negative: clip to t=0 (exact)
#pragma unroll
        for (int k = 0; k < WARM / 4; ++k) {
            const int t4 = w0t + 4 * k;
            if (t4 >= 0) {
                float4 xv[CDIM];
#pragma unroll
                for (int c = 0; c < CDIM; ++c)
                    xv[c] = *reinterpret_cast<const float4*>(xb + (size_t)c * TT + t4);
#pragma unroll
                for (int j = 0; j < 4; ++j) {
#pragma unroll
                    for (int c = 0; c < CDIM; ++c) {
                        const float xs = (j == 0) ? xv[c].x : (j == 1) ? xv[c].y
                                       : (j == 2) ? xv[c].z : xv[c].w;
                        y[c] = 0.5f * (xs + y[c]);
                    }
                }
            }
        }

#pragma unroll
        for (int k = 0; k < SEG / 4; ++k) {
            const int t4 = tstart + 4 * k;  // 125*24 = 3000: never clips
            float4 xv[CDIM];
#pragma unroll
            for (int c = 0; c < CDIM; ++c)
                xv[c] = *reinterpret_cast<const float4*>(xb + (size_t)c * TT + t4);
#pragma unroll
            for (int j = 0; j < 4; ++j) {
                float s2 = 0.0f;
#pragma unroll
                for (int c = 0; c < CDIM; ++c) {
                    const float xs = (j == 0) ? xv[c].x : (j == 1) ? xv[c].y
                                   : (j == 2) ? xv[c].z : xv[c].w;
                    y[c] = 0.5f * (xs + y[c]);
                    s2 = fmaf(y[c], y[c], s2);
                }
                if (s2 * wmax2 >= rhs2) {
                    const int i = atomicAdd(&cnt, 1);
                    if (i < CAP) {
                        ct[i] = t4 + j;
#pragma unroll
                        for (int c = 0; c < CDIM; ++c) cy[i][c] = y[c];
                    } else {
                        ovf = 1;           // benign race: all writers store 1
                    }
                }
            }
        }
    }
    __syncthreads();

    // ---- phase 3: exact per-neuron check of LDS candidates ----
    if (!trivial) {
        const int n = cnt < CAP ? cnt : CAP;
        bool myhit = false;
        for (int i = 0; i < n; ++i) {
            const int t = ct[i];
            float yv[CDIM];
#pragma unroll
            for (int c = 0; c < CDIM; ++c) yv[c] = cy[i][c];   // LDS broadcast
            const float factor = 1.0f - exp2f(-(float)(t + 1));
#pragma unroll
            for (int j = 0; j < 4; ++j) {
                const int r = tid * 4 + j;
                const float4* wr = reinterpret_cast<const float4*>(Win + (size_t)r * CDIM);
                const float4 w0 = wr[0], w1 = wr[1];
                const float a = w0.x * yv[0] + w0.y * yv[1] + w0.z * yv[2] + w0.w * yv[3] +
                                w1.x * yv[4] + w1.y * yv[5] + w1.z * yv[6] + w1.w * yv[7];
                const float v = a + (bin[r] + brec[r]) * factor;
                myhit = myhit || (v >= VTHR);
            }
        }
        if (myhit) hit = 1;                // benign race: all writers store 1
    }
    __syncthreads();

    const bool spike = trivial || (ovf != 0) || (hit != 0);

    if (!spike) {
        // provably no spikes in this batch: counts are exactly zero
        reinterpret_cast<float4*>(out + (size_t)b * RDIM)[tid] =
            make_float4(0.0f, 0.0f, 0.0f, 0.0f);
        return;
    }

    // ---- phase 4 (rare): exact full simulation of this batch ----
    const int wid  = tid >> 6;
    const int lane = tid & 63;
    const int r0   = tid * 4;

    float w[4][CDIM], bias[4], v[4], cntv[4];
#pragma unroll
    for (int j = 0; j < 4; ++j) {
        const int r = r0 + j;
#pragma unroll
        for (int c = 0; c < CDIM; ++c) w[j][c] = Win[r * CDIM + c];
        bias[j] = bin[r] + brec[r];
        v[j] = 0.0f;
        cntv[j] = 0.0f;
    }
    if (tid < 16) wmask[0][tid] = 0ULL;
    __syncthreads();

    const float* xb = x + (size_t)b * (CDIM * TT);

    for (int t = 0; t < TT; ++t) {
        const int p = t & 1, q = p ^ 1;
        float xv[CDIM];
#pragma unroll
        for (int c = 0; c < CDIM; ++c) xv[c] = xb[c * TT + t];

        float I[4];
#pragma unroll
        for (int j = 0; j < 4; ++j) {
            float a = bias[j];
#pragma unroll
            for (int c = 0; c < CDIM; ++c) a = fmaf(xv[c], w[j][c], a);
            I[j] = a;
        }
        for (int W = 0; W < 16; ++W) {
            unsigned long long mm = wmask[p][W];
            while (mm) {
                const int l = __ffsll(mm) - 1;
                mm &= mm - 1;
                const int rp = ((W >> 2) << 8) + (l << 2) + (W & 3);
#pragma unroll
                for (int j = 0; j < 4; ++j)
                    I[j] += Wrec[(size_t)(r0 + j) * RDIM + rp];
            }
        }
        unsigned long long bmv[4];
#pragma unroll
        for (int j = 0; j < 4; ++j) {
            float vv = v[j] + (I[j] - v[j]) * 0.5f;
            const bool sp = (vv - 1.0f) >= 0.0f;
            cntv[j] += sp ? 1.0f : 0.0f;
            v[j] = sp ? 0.0f : vv;
            bmv[j] = __ballot(sp);
        }
        if (lane == 0) {
#pragma unroll
            for (int j = 0; j < 4; ++j) wmask[q][wid * 4 + j] = bmv[j];
        }
        __syncthreads();
    }
#pragma unroll
    for (int j = 0; j < 4; ++j) out[(size_t)b * RDIM + r0 + j] = cntv[j];
}

// ---------------------------------------------------------------------------
extern "C" void kernel_launch(void* const* d_in, const int* in_sizes, int n_in,
                              void* d_out, int out_size, void* d_ws, size_t ws_size,
                              hipStream_t stream) {
    const float* x    = (const float*)d_in[0];
    const float* Win  = (const float*)d_in[1];
    const float* bin  = (const float*)d_in[2];
    const float* Wrec = (const float*)d_in[3];
    const float* brec = (const float*)d_in[4];
    float* out = (float*)d_out;
    (void)d_ws; (void)ws_size;

    hipLaunchKernelGGL(snn_all, dim3(BATCH), dim3(256), 0, stream,
                       x, Win, bin, Wrec, brec, out);
}

// Round 5
// 13.401 us; speedup vs baseline: 14.1479x; 1.3348x over previous
//
#include <hip/hip_runtime.h>

// SpikingJellyReservoirSNN: B=128, C=8, T=3000, R=1024
// v_{t+1} = 0.5*(v_t + I_t), spike iff v>=1, hard reset, count.
//
// Factorization (exact until the first spike): v is a linear filter of I, so
// with per-channel EWMA y_t = 0.5*x_t + 0.5*y_{t-1} (C=8 chains per batch):
//     v[b,r,t] = w_r . y[b,t] + bias_r * (1 - 2^-(t+1))
// Screen via Cauchy-Schwarz: v <= ||w_r||*||y_bt|| + max(bias_r, 0).
// (b,t) passing the screen (~1e-4 fraction) get an exact 1024-neuron check;
// if any neuron could truly cross (or the screen is inconclusive), the block
// falls through to the exact full simulation of ITS OWN batch — batches are
// independent, so one block per batch needs no cross-block data at all.
// ONE kernel launch, no workspace. Correct for ALL inputs; for this input the
// provable answer is all-zeros (a crossing would need a ~9-sigma event).
//
// R5: phase 2 rebuilt for latency hiding — SEG 24->12 (all 4 waves active),
// WARM 32->24, depth-4 ring-buffer prefetch (fully unrolled, static indices),
// prologue loads issued before the phase-1 weight reduction.

#define TT 3000
#define RDIM 1024
#define CDIM 8
#define BATCH 128
#define SEG 12          // timesteps per screen-thread; 250*12 = 3000 exactly
#define NSEG 250
#define WARM 24         // warmup steps; 2^-24 truncation vs 1e-3 margin;
                        // threads with tstart <= WARM warm exactly from t=0
#define NITER 9         // (WARM + SEG) / 4
#define NWARM 6         // WARM / 4
#define PFD 4           // prefetch depth (ring buffer)
#define CAP 128         // LDS candidate capacity; overflow -> full sim
#define VTHR 0.999f     // conservative vs true 1.0 (fp error ~1e-6)

__device__ __forceinline__ float f4elem(const float4& v, int j) {
    return (j == 0) ? v.x : (j == 1) ? v.y : (j == 2) ? v.z : v.w;
}

__global__ __launch_bounds__(256, 1) void snn_all(
    const float* __restrict__ x,     // [B, C, T]
    const float* __restrict__ Win,   // [R, C]
    const float* __restrict__ bin,   // [R]
    const float* __restrict__ Wrec,  // [R, R]
    const float* __restrict__ brec,  // [R]
    float* __restrict__ out)         // [B, R]
{
    const int b   = blockIdx.x;
    const int tid = threadIdx.x;

    __shared__ float rw[256], rb[256];
    __shared__ float cy[CAP][CDIM];
    __shared__ int   ct[CAP];
    __shared__ int   cnt, ovf, hit;
    __shared__ unsigned long long wmask[2][16];

    // ---- prologue: issue the first PFD x-tile loads NOW so their HBM
    //      latency hides under the phase-1 weight reduction ----
    const int  tstart = tid * SEG;
    const bool act    = (tid < NSEG);
    const float* xb   = x + (size_t)b * CDIM * TT;

    float4 buf[PFD][CDIM];
    // load iteration k into buf slot s (t4 < 0 lanes clamp to 0; their
    // contribution is skipped in the compute phase, so this stays exact)
    auto LOADK = [&](int k, int s) {
        const int t4 = tstart - WARM + 4 * k;
        const int tc = (t4 < 0) ? 0 : t4;
#pragma unroll
        for (int c = 0; c < CDIM; ++c)
            buf[s][c] = *reinterpret_cast<const float4*>(xb + (size_t)c * TT + tc);
    };
    if (act) {
#pragma unroll
        for (int k = 0; k < PFD; ++k) LOADK(k, k);
    }

    // ---- phase 1: wmax2 = max_r ||w_r||^2, bmax = max_r max(bias_r, 0) ----
    float wm = 0.0f, bm = -1e30f;
#pragma unroll
    for (int k = 0; k < 4; ++k) {
        const int r = tid + k * 256;
        const float4* wr = reinterpret_cast<const float4*>(Win + (size_t)r * CDIM);
        const float4 w0 = wr[0], w1 = wr[1];
        const float s = w0.x * w0.x + w0.y * w0.y + w0.z * w0.z + w0.w * w0.w +
                        w1.x * w1.x + w1.y * w1.y + w1.z * w1.z + w1.w * w1.w;
        wm = fmaxf(wm, s);
        bm = fmaxf(bm, bin[r] + brec[r]);
    }
    rw[tid] = wm;
    rb[tid] = bm;
    if (tid == 0) { cnt = 0; ovf = 0; hit = 0; }
    __syncthreads();
    for (int off = 128; off > 0; off >>= 1) {
        if (tid < off) {
            rw[tid] = fmaxf(rw[tid], rw[tid + off]);
            rb[tid] = fmaxf(rb[tid], rb[tid + off]);
        }
        __syncthreads();
    }
    const float wmax2   = rw[0];
    const float bmax    = fmaxf(rb[0], 0.0f);
    const float rhs     = VTHR - bmax;
    const bool  trivial = (rhs <= 0.0f);   // bias alone could cross
    const float rhs2    = rhs * rhs;

    // ---- phase 2: EWMA + inline screen, depth-4 software pipeline ----
    if (!trivial && act) {
        float y[CDIM];
#pragma unroll
        for (int c = 0; c < CDIM; ++c) y[c] = 0.0f;

#pragma unroll
        for (int k = 0; k < NITER; ++k) {
            const int t4 = tstart - WARM + 4 * k;
            if (k < NWARM) {
                // warmup: no screen; skip negative-t lanes (keeps t<WARM exact)
                if (t4 >= 0) {
#pragma unroll
                    for (int j = 0; j < 4; ++j)
#pragma unroll
                        for (int c = 0; c < CDIM; ++c)
                            y[c] = 0.5f * (f4elem(buf[k % PFD][c], j) + y[c]);
                }
            } else {
#pragma unroll
                for (int j = 0; j < 4; ++j) {
                    float s2 = 0.0f;
#pragma unroll
                    for (int c = 0; c < CDIM; ++c) {
                        y[c] = 0.5f * (f4elem(buf[k % PFD][c], j) + y[c]);
                        s2 = fmaf(y[c], y[c], s2);
                    }
                    if (s2 * wmax2 >= rhs2) {      // Cauchy-Schwarz screen
                        const int i = atomicAdd(&cnt, 1);
                        if (i < CAP) {
                            ct[i] = t4 + j;
#pragma unroll
                            for (int c = 0; c < CDIM; ++c) cy[i][c] = y[c];
                        } else {
                            ovf = 1;               // benign race: all store 1
                        }
                    }
                }
            }
            // refill the slot just consumed (stays in flight for PFD iters)
            if (k + PFD < NITER) LOADK(k + PFD, k % PFD);
        }
    }
    __syncthreads();

    // ---- phase 3: exact per-neuron check of LDS candidates ----
    if (!trivial) {
        const int n = cnt < CAP ? cnt : CAP;
        bool myhit = false;
        for (int i = 0; i < n; ++i) {
            const int t = ct[i];
            float yv[CDIM];
#pragma unroll
            for (int c = 0; c < CDIM; ++c) yv[c] = cy[i][c];   // LDS broadcast
            const float factor = 1.0f - exp2f(-(float)(t + 1));
#pragma unroll
            for (int j = 0; j < 4; ++j) {
                const int r = tid * 4 + j;
                const float4* wr = reinterpret_cast<const float4*>(Win + (size_t)r * CDIM);
                const float4 w0 = wr[0], w1 = wr[1];
                const float a = w0.x * yv[0] + w0.y * yv[1] + w0.z * yv[2] + w0.w * yv[3] +
                                w1.x * yv[4] + w1.y * yv[5] + w1.z * yv[6] + w1.w * yv[7];
                const float v = a + (bin[r] + brec[r]) * factor;
                myhit = myhit || (v >= VTHR);
            }
        }
        if (myhit) hit = 1;                // benign race: all writers store 1
    }
    __syncthreads();

    const bool spike = trivial || (ovf != 0) || (hit != 0);

    if (!spike) {
        // provably no spikes in this batch: counts are exactly zero
        reinterpret_cast<float4*>(out + (size_t)b * RDIM)[tid] =
            make_float4(0.0f, 0.0f, 0.0f, 0.0f);
        return;
    }

    // ---- phase 4 (rare): exact full simulation of this batch ----
    const int wid  = tid >> 6;
    const int lane = tid & 63;
    const int r0   = tid * 4;

    float w[4][CDIM], bias[4], v[4], cntv[4];
#pragma unroll
    for (int j = 0; j < 4; ++j) {
        const int r = r0 + j;
#pragma unroll
        for (int c = 0; c < CDIM; ++c) w[j][c] = Win[r * CDIM + c];
        bias[j] = bin[r] + brec[r];
        v[j] = 0.0f;
        cntv[j] = 0.0f;
    }
    if (tid < 16) wmask[0][tid] = 0ULL;
    __syncthreads();

    const float* xbt = x + (size_t)b * (CDIM * TT);

    for (int t = 0; t < TT; ++t) {
        const int p = t & 1, q = p ^ 1;
        float xv[CDIM];
#pragma unroll
        for (int c = 0; c < CDIM; ++c) xv[c] = xbt[c * TT + t];

        float I[4];
#pragma unroll
        for (int j = 0; j < 4; ++j) {
            float a = bias[j];
#pragma unroll
            for (int c = 0; c < CDIM; ++c) a = fmaf(xv[c], w[j][c], a);
            I[j] = a;
        }
        for (int W = 0; W < 16; ++W) {
            unsigned long long mm = wmask[p][W];
            while (mm) {
                const int l = __ffsll(mm) - 1;
                mm &= mm - 1;
                const int rp = ((W >> 2) << 8) + (l << 2) + (W & 3);
#pragma unroll
                for (int j = 0; j < 4; ++j)
                    I[j] += Wrec[(size_t)(r0 + j) * RDIM + rp];
            }
        }
        unsigned long long bmv[4];
#pragma unroll
        for (int j = 0; j < 4; ++j) {
            float vv = v[j] + (I[j] - v[j]) * 0.5f;
            const bool sp = (vv - 1.0f) >= 0.0f;
            cntv[j] += sp ? 1.0f : 0.0f;
            v[j] = sp ? 0.0f : vv;
            bmv[j] = __ballot(sp);
        }
        if (lane == 0) {
#pragma unroll
            for (int j = 0; j < 4; ++j) wmask[q][wid * 4 + j] = bmv[j];
        }
        __syncthreads();
    }
#pragma unroll
    for (int j = 0; j < 4; ++j) out[(size_t)b * RDIM + r0 + j] = cntv[j];
}

// ---------------------------------------------------------------------------
extern "C" void kernel_launch(void* const* d_in, const int* in_sizes, int n_in,
                              void* d_out, int out_size, void* d_ws, size_t ws_size,
                              hipStream_t stream) {
    const float* x    = (const float*)d_in[0];
    const float* Win  = (const float*)d_in[1];
    const float* bin  = (const float*)d_in[2];
    const float* Wrec = (const float*)d_in[3];
    const float* brec = (const float*)d_in[4];
    float* out = (float*)d_out;
    (void)d_ws; (void)ws_size;

    hipLaunchKernelGGL(snn_all, dim3(BATCH), dim3(256), 0, stream,
                       x, Win, bin, Wrec, brec, out);
}

// Round 6
// 11.977 us; speedup vs baseline: 15.8294x; 1.1188x over previous
//
#include <hip/hip_runtime.h>

// SpikingJellyReservoirSNN: B=128, C=8, T=3000, R=1024
// v_{t+1} = 0.5*(v_t + I_t), spike iff v>=1, hard reset, count.
//
// Factorization (exact until the first spike): v is a linear filter of I, so
// with per-channel EWMA y_t = 0.5*x_t + 0.5*y_{t-1} (C=8 chains per batch):
//     v[b,r,t] = w_r . y[b,t] + bias_r * (1 - 2^-(t+1))
// Screen via Cauchy-Schwarz: v <= ||w_r||*||y_bt|| + max(bias_r, 0).
// (b,t) passing the screen (~1e-4 fraction) get an exact 1024-neuron check;
// if any neuron could truly cross (or the screen is inconclusive), the block
// falls through to the exact full simulation of ITS OWN batch — batches are
// independent, so one block per batch needs no cross-block data at all.
// ONE kernel launch, no workspace. Correct for ALL inputs; for this input the
// provable answer is all-zeros (a crossing would need a ~9-sigma event).
//
// R6: WARM 24->16 (NITER 7); FULL x prefetch (all 7 tiles, 224 VGPR, issued
// after the Win/bias loads so phase 1 runs at vmcnt(56) with x in flight);
// phase-1 reduction via wave shuffles + single LDS exchange (2 barriers).

#define TT 3000
#define RDIM 1024
#define CDIM 8
#define BATCH 128
#define SEG 12          // timesteps per screen-thread; 250*12 = 3000 exactly
#define NSEG 250
#define WARM 16         // warmup steps; 2^-16 * ||y|| * ||w|| ~ 1e-5 << 1e-3
#define NITER 7         // (WARM + SEG) / 4
#define NWARM 4         // WARM / 4
#define CAP 128         // LDS candidate capacity; overflow -> full sim
#define VTHR 0.999f     // conservative vs true 1.0 (fp error ~1e-6)

__device__ __forceinline__ float f4elem(const float4& v, int j) {
    return (j == 0) ? v.x : (j == 1) ? v.y : (j == 2) ? v.z : v.w;
}

__global__ __launch_bounds__(256, 1) void snn_all(
    const float* __restrict__ x,     // [B, C, T]
    const float* __restrict__ Win,   // [R, C]
    const float* __restrict__ bin,   // [R]
    const float* __restrict__ Wrec,  // [R, R]
    const float* __restrict__ brec,  // [R]
    float* __restrict__ out)         // [B, R]
{
    const int b   = blockIdx.x;
    const int tid = threadIdx.x;

    __shared__ float rw[4], rb[4];
    __shared__ float cy[CAP][CDIM];
    __shared__ int   ct[CAP];
    __shared__ int   cnt, ovf, hit;
    __shared__ unsigned long long wmask[2][16];

    const int  tstart = tid * SEG;
    const bool act    = (tid < NSEG);
    const float* xb   = x + (size_t)b * CDIM * TT;

    // ---- issue weight/bias loads FIRST (phase 1 consumes at vmcnt(56)) ----
    // r = 4*tid + j mapping: 8 float4 of Win rows + 2 float4 of biases
    const int r0 = tid * 4;
    float4 wv[8], bn4, br4;
#pragma unroll
    for (int j = 0; j < 4; ++j) {
        const float4* wr = reinterpret_cast<const float4*>(Win + (size_t)(r0 + j) * CDIM);
        wv[2 * j]     = wr[0];
        wv[2 * j + 1] = wr[1];
    }
    bn4 = *reinterpret_cast<const float4*>(bin + r0);
    br4 = *reinterpret_cast<const float4*>(brec + r0);

    // ---- full x prefetch: all NITER tiles in flight (static indices) ----
    float4 buf[NITER][CDIM];
    if (act) {
#pragma unroll
        for (int k = 0; k < NITER; ++k) {
            const int t4 = tstart - WARM + 4 * k;
            const int tc = (t4 < 0) ? 0 : t4;   // clamped loads are skipped later
#pragma unroll
            for (int c = 0; c < CDIM; ++c)
                buf[k][c] = *reinterpret_cast<const float4*>(xb + (size_t)c * TT + tc);
        }
    }

    if (tid == 0) { cnt = 0; ovf = 0; hit = 0; }

    // ---- phase 1: wmax2 = max_r ||w_r||^2, bmax = max_r max(bias_r,0) ----
    float wm = 0.0f, bm = -1e30f;
#pragma unroll
    for (int j = 0; j < 4; ++j) {
        const float4 w0 = wv[2 * j], w1 = wv[2 * j + 1];
        const float s = w0.x * w0.x + w0.y * w0.y + w0.z * w0.z + w0.w * w0.w +
                        w1.x * w1.x + w1.y * w1.y + w1.z * w1.z + w1.w * w1.w;
        wm = fmaxf(wm, s);
        bm = fmaxf(bm, f4elem(bn4, j) + f4elem(br4, j));
    }
    // wave-level butterfly (64 lanes, no barriers)
#pragma unroll
    for (int off = 1; off < 64; off <<= 1) {
        wm = fmaxf(wm, __shfl_xor(wm, off, 64));
        bm = fmaxf(bm, __shfl_xor(bm, off, 64));
    }
    if ((tid & 63) == 0) { rw[tid >> 6] = wm; rb[tid >> 6] = bm; }
    __syncthreads();
    const float wmax2 = fmaxf(fmaxf(rw[0], rw[1]), fmaxf(rw[2], rw[3]));
    const float bmax  = fmaxf(fmaxf(fmaxf(rb[0], rb[1]), fmaxf(rb[2], rb[3])), 0.0f);
    const float rhs     = VTHR - bmax;
    const bool  trivial = (rhs <= 0.0f);   // bias alone could cross
    const float rhs2    = rhs * rhs;

    // ---- phase 2: EWMA + inline Cauchy-Schwarz screen (all data resident) ----
    if (!trivial && act) {
        float y[CDIM];
#pragma unroll
        for (int c = 0; c < CDIM; ++c) y[c] = 0.0f;

#pragma unroll
        for (int k = 0; k < NITER; ++k) {
            const int t4 = tstart - WARM + 4 * k;
            if (k < NWARM) {
                // warmup: no screen; skip negative-t tiles (t<WARM stays exact)
                if (t4 >= 0) {
#pragma unroll
                    for (int j = 0; j < 4; ++j)
#pragma unroll
                        for (int c = 0; c < CDIM; ++c)
                            y[c] = 0.5f * (f4elem(buf[k][c], j) + y[c]);
                }
            } else {
#pragma unroll
                for (int j = 0; j < 4; ++j) {
                    float s2 = 0.0f;
#pragma unroll
                    for (int c = 0; c < CDIM; ++c) {
                        y[c] = 0.5f * (f4elem(buf[k][c], j) + y[c]);
                        s2 = fmaf(y[c], y[c], s2);
                    }
                    if (s2 * wmax2 >= rhs2) {
                        const int i = atomicAdd(&cnt, 1);
                        if (i < CAP) {
                            ct[i] = t4 + j;
#pragma unroll
                            for (int c = 0; c < CDIM; ++c) cy[i][c] = y[c];
                        } else {
                            ovf = 1;       // benign race: all writers store 1
                        }
                    }
                }
            }
        }
    }
    __syncthreads();

    // ---- phase 3: exact per-neuron check of LDS candidates ----
    if (!trivial) {
        const int n = cnt < CAP ? cnt : CAP;
        bool myhit = false;
        for (int i = 0; i < n; ++i) {
            const int t = ct[i];
            float yv[CDIM];
#pragma unroll
            for (int c = 0; c < CDIM; ++c) yv[c] = cy[i][c];   // LDS broadcast
            const float factor = 1.0f - exp2f(-(float)(t + 1));
#pragma unroll
            for (int j = 0; j < 4; ++j) {
                const float4 w0 = wv[2 * j], w1 = wv[2 * j + 1];
                const float a = w0.x * yv[0] + w0.y * yv[1] + w0.z * yv[2] + w0.w * yv[3] +
                                w1.x * yv[4] + w1.y * yv[5] + w1.z * yv[6] + w1.w * yv[7];
                const float v = a + (f4elem(bn4, j) + f4elem(br4, j)) * factor;
                myhit = myhit || (v >= VTHR);
            }
        }
        if (myhit) hit = 1;                // benign race: all writers store 1
    }
    __syncthreads();

    const bool spike = trivial || (ovf != 0) || (hit != 0);

    if (!spike) {
        // provably no spikes in this batch: counts are exactly zero
        reinterpret_cast<float4*>(out + (size_t)b * RDIM)[tid] =
            make_float4(0.0f, 0.0f, 0.0f, 0.0f);
        return;
    }

    // ---- phase 4 (rare): exact full simulation of this batch ----
    const int wid  = tid >> 6;
    const int lane = tid & 63;

    float w[4][CDIM], bias[4], v[4], cntv[4];
#pragma unroll
    for (int j = 0; j < 4; ++j) {
#pragma unroll
        for (int c = 0; c < 4; ++c) {
            w[j][c]     = f4elem(wv[2 * j], c);
            w[j][4 + c] = f4elem(wv[2 * j + 1], c);
        }
        bias[j] = f4elem(bn4, j) + f4elem(br4, j);
        v[j] = 0.0f;
        cntv[j] = 0.0f;
    }
    if (tid < 16) wmask[0][tid] = 0ULL;
    __syncthreads();

    const float* xbt = x + (size_t)b * (CDIM * TT);

    for (int t = 0; t < TT; ++t) {
        const int p = t & 1, q = p ^ 1;
        float xv[CDIM];
#pragma unroll
        for (int c = 0; c < CDIM; ++c) xv[c] = xbt[c * TT + t];

        float I[4];
#pragma unroll
        for (int j = 0; j < 4; ++j) {
            float a = bias[j];
#pragma unroll
            for (int c = 0; c < CDIM; ++c) a = fmaf(xv[c], w[j][c], a);
            I[j] = a;
        }
        for (int W = 0; W < 16; ++W) {
            unsigned long long mm = wmask[p][W];
            while (mm) {
                const int l = __ffsll(mm) - 1;
                mm &= mm - 1;
                const int rp = ((W >> 2) << 8) + (l << 2) + (W & 3);
#pragma unroll
                for (int j = 0; j < 4; ++j)
                    I[j] += Wrec[(size_t)(r0 + j) * RDIM + rp];
            }
        }
        unsigned long long bmv[4];
#pragma unroll
        for (int j = 0; j < 4; ++j) {
            float vv = v[j] + (I[j] - v[j]) * 0.5f;
            const bool sp = (vv - 1.0f) >= 0.0f;
            cntv[j] += sp ? 1.0f : 0.0f;
            v[j] = sp ? 0.0f : vv;
            bmv[j] = __ballot(sp);
        }
        if (lane == 0) {
#pragma unroll
            for (int j = 0; j < 4; ++j) wmask[q][wid * 4 + j] = bmv[j];
        }
        __syncthreads();
    }
#pragma unroll
    for (int j = 0; j < 4; ++j) out[(size_t)b * RDIM + r0 + j] = cntv[j];
}

// ---------------------------------------------------------------------------
extern "C" void kernel_launch(void* const* d_in, const int* in_sizes, int n_in,
                              void* d_out, int out_size, void* d_ws, size_t ws_size,
                              hipStream_t stream) {
    const float* x    = (const float*)d_in[0];
    const float* Win  = (const float*)d_in[1];
    const float* bin  = (const float*)d_in[2];
    const float* Wrec = (const float*)d_in[3];
    const float* brec = (const float*)d_in[4];
    float* out = (float*)d_out;
    (void)d_ws; (void)ws_size;

    hipLaunchKernelGGL(snn_all, dim3(BATCH), dim3(256), 0, stream,
                       x, Win, bin, Wrec, brec, out);
}

// Round 7
// 11.494 us; speedup vs baseline: 16.4949x; 1.0420x over previous
//
#include <hip/hip_runtime.h>

// SpikingJellyReservoirSNN: B=128, C=8, T=3000, R=1024
// v_{t+1} = 0.5*(v_t + I_t), spike iff v>=1, hard reset, count.
//
// Factorization (exact until the first spike): v is a linear filter of I, so
// with per-channel EWMA y_t = 0.5*x_t + 0.5*y_{t-1} (C=8 chains per batch):
//     v[b,r,t] = w_r . y[b,t] + bias_r * (1 - 2^-(t+1))
// Screen via Cauchy-Schwarz: v <= ||w_r||*||y_bt|| + max(bias_r, 0).
// (b,t) passing the screen (~1e-4 fraction) get an exact 1024-neuron check;
// if any neuron could truly cross (or the screen is inconclusive), the block
// falls through to the exact full simulation of ITS OWN batch — batches are
// independent, so one block per batch needs no cross-block data at all.
// ONE kernel launch, no workspace. Correct for ALL inputs; for this input the
// provable answer is all-zeros (a crossing would need a ~9-sigma event).
//
// R7: warm-up recomputation replaced by an EXACT affine scan. Each 12-step
// segment is y_out = 2^-12 * y_in + b; an exclusive scan of affine
// compositions (6 shfl_up rounds intra-wave + 4-entry LDS cross-wave) gives
// every thread its exact starting state. x is loaded exactly once
// (24 float4/thread, was 56), and the screen has no truncation error at all.

#define TT 3000
#define RDIM 1024
#define CDIM 8
#define BATCH 128
#define SEG 12          // timesteps per screen-thread; 250*12 = 3000 exactly
#define NSEG 250
#define NT 3            // float4 tiles per segment (SEG/4)
#define A_SEG 0.000244140625f   // 2^-12, exact in fp32
#define CAP 128         // LDS candidate capacity; overflow -> full sim
#define VTHR 0.999f     // margin vs true 1.0 (covers ~1e-6 fp noise)

__device__ __forceinline__ float f4elem(const float4& v, int j) {
    return (j == 0) ? v.x : (j == 1) ? v.y : (j == 2) ? v.z : v.w;
}

__global__ __launch_bounds__(256, 1) void snn_all(
    const float* __restrict__ x,     // [B, C, T]
    const float* __restrict__ Win,   // [R, C]
    const float* __restrict__ bin,   // [R]
    const float* __restrict__ Wrec,  // [R, R]
    const float* __restrict__ brec,  // [R]
    float* __restrict__ out)         // [B, R]
{
    const int b   = blockIdx.x;
    const int tid = threadIdx.x;
    const int wid  = tid >> 6;
    const int lane = tid & 63;

    __shared__ float rw[4], rb[4];
    __shared__ float sA[4], sB[4][CDIM];   // per-wave scan partials
    __shared__ float cy[CAP][CDIM];
    __shared__ int   ct[CAP];
    __shared__ int   cnt, ovf, hit;
    __shared__ unsigned long long wmask[2][16];

    const int  tstart = tid * SEG;
    const bool act    = (tid < NSEG);
    const float* xb   = x + (size_t)b * CDIM * TT;

    // ---- issue weight/bias loads FIRST, then the segment's x tiles ----
    const int r0 = tid * 4;
    float4 wv[8], bn4, br4;
#pragma unroll
    for (int j = 0; j < 4; ++j) {
        const float4* wr = reinterpret_cast<const float4*>(Win + (size_t)(r0 + j) * CDIM);
        wv[2 * j]     = wr[0];
        wv[2 * j + 1] = wr[1];
    }
    bn4 = *reinterpret_cast<const float4*>(bin + r0);
    br4 = *reinterpret_cast<const float4*>(brec + r0);

    float4 buf[NT][CDIM];                 // exactly this thread's 12 steps
    if (act) {
#pragma unroll
        for (int k = 0; k < NT; ++k)
#pragma unroll
            for (int c = 0; c < CDIM; ++c)
                buf[k][c] = *reinterpret_cast<const float4*>(
                    xb + (size_t)c * TT + tstart + 4 * k);
    }

    if (tid == 0) { cnt = 0; ovf = 0; hit = 0; }

    // ---- phase 1: wmax2 = max_r ||w_r||^2, bmax = max_r max(bias_r,0) ----
    float wm = 0.0f, bm = -1e30f;
#pragma unroll
    for (int j = 0; j < 4; ++j) {
        const float4 w0 = wv[2 * j], w1 = wv[2 * j + 1];
        const float s = w0.x * w0.x + w0.y * w0.y + w0.z * w0.z + w0.w * w0.w +
                        w1.x * w1.x + w1.y * w1.y + w1.z * w1.z + w1.w * w1.w;
        wm = fmaxf(wm, s);
        bm = fmaxf(bm, f4elem(bn4, j) + f4elem(br4, j));
    }
#pragma unroll
    for (int off = 1; off < 64; off <<= 1) {
        wm = fmaxf(wm, __shfl_xor(wm, off, 64));
        bm = fmaxf(bm, __shfl_xor(bm, off, 64));
    }
    if (lane == 0) { rw[wid] = wm; rb[wid] = bm; }
    __syncthreads();
    const float wmax2 = fmaxf(fmaxf(rw[0], rw[1]), fmaxf(rw[2], rw[3]));
    const float bmax  = fmaxf(fmaxf(fmaxf(rb[0], rb[1]), fmaxf(rb[2], rb[3])), 0.0f);
    const float rhs     = VTHR - bmax;
    const bool  trivial = (rhs <= 0.0f);   // bias alone could cross
    const float rhs2    = rhs * rhs;

    if (!trivial) {
        // ---- local pass: segment as affine map y_out = A*y_in + bl ----
        float A = 1.0f;
        float bl[CDIM];
#pragma unroll
        for (int c = 0; c < CDIM; ++c) bl[c] = 0.0f;
        if (act) {
#pragma unroll
            for (int k = 0; k < NT; ++k)
#pragma unroll
                for (int j = 0; j < 4; ++j)
#pragma unroll
                    for (int c = 0; c < CDIM; ++c)
                        bl[c] = 0.5f * (f4elem(buf[k][c], j) + bl[c]);
            A = A_SEG;
        }

        // ---- intra-wave inclusive scan of affine composition ----
        // combine earlier (A',B') into self (later): B = A*B' + B; A = A*A'
#pragma unroll
        for (int d = 1; d < 64; d <<= 1) {
            const float Ap = __shfl_up(A, (unsigned)d, 64);
            float Bp[CDIM];
#pragma unroll
            for (int c = 0; c < CDIM; ++c) Bp[c] = __shfl_up(bl[c], (unsigned)d, 64);
            if (lane >= d) {
#pragma unroll
                for (int c = 0; c < CDIM; ++c) bl[c] = fmaf(A, Bp[c], bl[c]);
                A *= Ap;
            }
        }

        // exclusive within wave (shift by one; lane 0 = identity)
        float Ae = __shfl_up(A, 1u, 64);
        float Be[CDIM];
#pragma unroll
        for (int c = 0; c < CDIM; ++c) Be[c] = __shfl_up(bl[c], 1u, 64);
        if (lane == 0) {
            Ae = 1.0f;
#pragma unroll
            for (int c = 0; c < CDIM; ++c) Be[c] = 0.0f;
        }

        // wave partials -> LDS, then compose prefix of earlier waves
        if (lane == 63) {
            sA[wid] = A;
#pragma unroll
            for (int c = 0; c < CDIM; ++c) sB[wid][c] = bl[c];
        }
        __syncthreads();

        float PB[CDIM];                    // (prefix of waves < wid)(0)
#pragma unroll
        for (int c = 0; c < CDIM; ++c) PB[c] = 0.0f;
        for (int w = 0; w < wid; ++w) {    // <= 3 iterations, LDS broadcasts
            const float Aw = sA[w];
#pragma unroll
            for (int c = 0; c < CDIM; ++c) PB[c] = fmaf(Aw, PB[c], sB[w][c]);
        }

        // ---- pass 2: exact EWMA from scanned start + inline screen ----
        if (act) {
            float y[CDIM];
#pragma unroll
            for (int c = 0; c < CDIM; ++c) y[c] = fmaf(Ae, PB[c], Be[c]);

#pragma unroll
            for (int k = 0; k < NT; ++k) {
#pragma unroll
                for (int j = 0; j < 4; ++j) {
                    float s2 = 0.0f;
#pragma unroll
                    for (int c = 0; c < CDIM; ++c) {
                        y[c] = 0.5f * (f4elem(buf[k][c], j) + y[c]);
                        s2 = fmaf(y[c], y[c], s2);
                    }
                    if (s2 * wmax2 >= rhs2) {      // Cauchy-Schwarz screen
                        const int i = atomicAdd(&cnt, 1);
                        if (i < CAP) {
                            ct[i] = tstart + 4 * k + j;
#pragma unroll
                            for (int c = 0; c < CDIM; ++c) cy[i][c] = y[c];
                        } else {
                            ovf = 1;       // benign race: all writers store 1
                        }
                    }
                }
            }
        }
    }
    __syncthreads();

    // ---- phase 3: exact per-neuron check of LDS candidates ----
    if (!trivial) {
        const int n = cnt < CAP ? cnt : CAP;
        bool myhit = false;
        for (int i = 0; i < n; ++i) {
            const int t = ct[i];
            float yv[CDIM];
#pragma unroll
            for (int c = 0; c < CDIM; ++c) yv[c] = cy[i][c];   // LDS broadcast
            const float factor = 1.0f - exp2f(-(float)(t + 1));
#pragma unroll
            for (int j = 0; j < 4; ++j) {
                const float4 w0 = wv[2 * j], w1 = wv[2 * j + 1];
                const float a = w0.x * yv[0] + w0.y * yv[1] + w0.z * yv[2] + w0.w * yv[3] +
                                w1.x * yv[4] + w1.y * yv[5] + w1.z * yv[6] + w1.w * yv[7];
                const float v = a + (f4elem(bn4, j) + f4elem(br4, j)) * factor;
                myhit = myhit || (v >= VTHR);
            }
        }
        if (myhit) hit = 1;                // benign race: all writers store 1
    }
    __syncthreads();

    const bool spike = trivial || (ovf != 0) || (hit != 0);

    if (!spike) {
        // provably no spikes in this batch: counts are exactly zero
        reinterpret_cast<float4*>(out + (size_t)b * RDIM)[tid] =
            make_float4(0.0f, 0.0f, 0.0f, 0.0f);
        return;
    }

    // ---- phase 4 (rare): exact full simulation of this batch ----
    float w[4][CDIM], bias[4], v[4], cntv[4];
#pragma unroll
    for (int j = 0; j < 4; ++j) {
#pragma unroll
        for (int c = 0; c < 4; ++c) {
            w[j][c]     = f4elem(wv[2 * j], c);
            w[j][4 + c] = f4elem(wv[2 * j + 1], c);
        }
        bias[j] = f4elem(bn4, j) + f4elem(br4, j);
        v[j] = 0.0f;
        cntv[j] = 0.0f;
    }
    if (tid < 16) wmask[0][tid] = 0ULL;
    __syncthreads();

    const float* xbt = x + (size_t)b * (CDIM * TT);

    for (int t = 0; t < TT; ++t) {
        const int p = t & 1, q = p ^ 1;
        float xv[CDIM];
#pragma unroll
        for (int c = 0; c < CDIM; ++c) xv[c] = xbt[c * TT + t];

        float I[4];
#pragma unroll
        for (int j = 0; j < 4; ++j) {
            float a = bias[j];
#pragma unroll
            for (int c = 0; c < CDIM; ++c) a = fmaf(xv[c], w[j][c], a);
            I[j] = a;
        }
        for (int W = 0; W < 16; ++W) {
            unsigned long long mm = wmask[p][W];
            while (mm) {
                const int l = __ffsll(mm) - 1;
                mm &= mm - 1;
                const int rp = ((W >> 2) << 8) + (l << 2) + (W & 3);
#pragma unroll
                for (int j = 0; j < 4; ++j)
                    I[j] += Wrec[(size_t)(r0 + j) * RDIM + rp];
            }
        }
        unsigned long long bmv[4];
#pragma unroll
        for (int j = 0; j < 4; ++j) {
            float vv = v[j] + (I[j] - v[j]) * 0.5f;
            const bool sp = (vv - 1.0f) >= 0.0f;
            cntv[j] += sp ? 1.0f : 0.0f;
            v[j] = sp ? 0.0f : vv;
            bmv[j] = __ballot(sp);
        }
        if (lane == 0) {
#pragma unroll
            for (int j = 0; j < 4; ++j) wmask[q][wid * 4 + j] = bmv[j];
        }
        __syncthreads();
    }
#pragma unroll
    for (int j = 0; j < 4; ++j) out[(size_t)b * RDIM + r0 + j] = cntv[j];
}

// ---------------------------------------------------------------------------
extern "C" void kernel_launch(void* const* d_in, const int* in_sizes, int n_in,
                              void* d_out, int out_size, void* d_ws, size_t ws_size,
                              hipStream_t stream) {
    const float* x    = (const float*)d_in[0];
    const float* Win  = (const float*)d_in[1];
    const float* bin  = (const float*)d_in[2];
    const float* Wrec = (const float*)d_in[3];
    const float* brec = (const float*)d_in[4];
    float* out = (float*)d_out;
    (void)d_ws; (void)ws_size;

    hipLaunchKernelGGL(snn_all, dim3(BATCH), dim3(256), 0, stream,
                       x, Win, bin, Wrec, brec, out);
}

// Round 8
// 11.346 us; speedup vs baseline: 16.7103x; 1.0131x over previous
//
#include <hip/hip_runtime.h>

// SpikingJellyReservoirSNN: B=128, C=8, T=3000, R=1024
// v_{t+1} = 0.5*(v_t + I_t), spike iff v>=1, hard reset, count.
//
// Factorization (exact until the first spike): v is a linear filter of I, so
// with per-channel EWMA y_t = 0.5*x_t + 0.5*y_{t-1} (C=8 chains per batch):
//     v[b,r,t] = w_r . y[b,t] + bias_r * (1 - 2^-(t+1))
// Screen via Cauchy-Schwarz: v <= ||w_r||*||y_bt|| + max(bias_r, 0).
// (b,t) passing the screen (~1e-4 fraction) get an exact 1024-neuron check;
// if any neuron could truly cross (or the screen is inconclusive), the block
// falls through to the exact full simulation of ITS OWN batch — batches are
// independent, so one block per batch needs no cross-block data at all.
// ONE kernel launch, no workspace. Correct for ALL inputs; for this input the
// provable answer is all-zeros (a crossing would need a ~9-sigma event).
//
// R8: blocks widened 256->512 threads (8 waves, 2/SIMD) for latency/barrier
// co-hiding; SEG 12->6 (500/512 threads active); exact affine scan kept
// (segment map y_out = 2^-6 y_in + b, shfl_up scan + 8-entry LDS exchange);
// phases 1/3/4 re-indexed to 2 neurons/thread.

#define TT 3000
#define RDIM 1024
#define CDIM 8
#define BATCH 128
#define NTH 512
#define SEG 6           // timesteps per screen-thread; 500*6 = 3000 exactly
#define NSEG 500
#define NT2 3           // float2 tiles per segment (SEG/2)
#define A_SEG 0.015625f // 2^-6, exact in fp32
#define CAP 128         // LDS candidate capacity; overflow -> full sim
#define VTHR 0.999f     // margin vs true 1.0 (covers ~1e-6 fp noise)

__device__ __forceinline__ float f2elem(const float2& v, int j) {
    return (j == 0) ? v.x : v.y;
}
__device__ __forceinline__ float f4elem(const float4& v, int j) {
    return (j == 0) ? v.x : (j == 1) ? v.y : (j == 2) ? v.z : v.w;
}

__global__ __launch_bounds__(NTH, 1) void snn_all(
    const float* __restrict__ x,     // [B, C, T]
    const float* __restrict__ Win,   // [R, C]
    const float* __restrict__ bin,   // [R]
    const float* __restrict__ Wrec,  // [R, R]
    const float* __restrict__ brec,  // [R]
    float* __restrict__ out)         // [B, R]
{
    const int b    = blockIdx.x;
    const int tid  = threadIdx.x;
    const int wid  = tid >> 6;       // 0..7
    const int lane = tid & 63;

    __shared__ float rw[8], rb[8];
    __shared__ float sA[8], sB[8][CDIM];   // per-wave scan partials
    __shared__ float cy[CAP][CDIM];
    __shared__ int   ct[CAP];
    __shared__ int   cnt, ovf, hit;
    __shared__ unsigned long long wmask[2][16];

    const int  tstart = tid * SEG;
    const bool act    = (tid < NSEG);
    const float* xb   = x + (size_t)b * CDIM * TT;

    // ---- issue weight/bias loads FIRST, then the segment's x tiles ----
    const int r0 = tid * 2;
    float4 wv[4];
    float2 bn2, br2;
#pragma unroll
    for (int j = 0; j < 2; ++j) {
        const float4* wr = reinterpret_cast<const float4*>(Win + (size_t)(r0 + j) * CDIM);
        wv[2 * j]     = wr[0];
        wv[2 * j + 1] = wr[1];
    }
    bn2 = *reinterpret_cast<const float2*>(bin + r0);
    br2 = *reinterpret_cast<const float2*>(brec + r0);

    float2 buf[NT2][CDIM];                // exactly this thread's 6 steps
    if (act) {
#pragma unroll
        for (int k = 0; k < NT2; ++k)
#pragma unroll
            for (int c = 0; c < CDIM; ++c)
                buf[k][c] = *reinterpret_cast<const float2*>(
                    xb + (size_t)c * TT + tstart + 2 * k);
    }

    if (tid == 0) { cnt = 0; ovf = 0; hit = 0; }

    // ---- phase 1: wmax2 = max_r ||w_r||^2, bmax = max_r max(bias_r,0) ----
    float wm = 0.0f, bm = -1e30f;
#pragma unroll
    for (int j = 0; j < 2; ++j) {
        const float4 w0 = wv[2 * j], w1 = wv[2 * j + 1];
        const float s = w0.x * w0.x + w0.y * w0.y + w0.z * w0.z + w0.w * w0.w +
                        w1.x * w1.x + w1.y * w1.y + w1.z * w1.z + w1.w * w1.w;
        wm = fmaxf(wm, s);
        bm = fmaxf(bm, f2elem(bn2, j) + f2elem(br2, j));
    }
#pragma unroll
    for (int off = 1; off < 64; off <<= 1) {
        wm = fmaxf(wm, __shfl_xor(wm, off, 64));
        bm = fmaxf(bm, __shfl_xor(bm, off, 64));
    }
    if (lane == 0) { rw[wid] = wm; rb[wid] = bm; }
    __syncthreads();
    float wmax2 = rw[0], bmax = rb[0];
#pragma unroll
    for (int wq = 1; wq < 8; ++wq) {
        wmax2 = fmaxf(wmax2, rw[wq]);
        bmax  = fmaxf(bmax, rb[wq]);
    }
    bmax = fmaxf(bmax, 0.0f);
    const float rhs     = VTHR - bmax;
    const bool  trivial = (rhs <= 0.0f);   // bias alone could cross
    const float rhs2    = rhs * rhs;

    if (!trivial) {
        // ---- local pass: segment as affine map y_out = A*y_in + bl ----
        float A = 1.0f;
        float bl[CDIM];
#pragma unroll
        for (int c = 0; c < CDIM; ++c) bl[c] = 0.0f;
        if (act) {
#pragma unroll
            for (int k = 0; k < NT2; ++k)
#pragma unroll
                for (int j = 0; j < 2; ++j)
#pragma unroll
                    for (int c = 0; c < CDIM; ++c)
                        bl[c] = 0.5f * (f2elem(buf[k][c], j) + bl[c]);
            A = A_SEG;
        }

        // ---- intra-wave inclusive scan of affine composition ----
        // combine earlier (A',B') into self (later): B = A*B' + B; A = A*A'
#pragma unroll
        for (int d = 1; d < 64; d <<= 1) {
            const float Ap = __shfl_up(A, (unsigned)d, 64);
            float Bp[CDIM];
#pragma unroll
            for (int c = 0; c < CDIM; ++c) Bp[c] = __shfl_up(bl[c], (unsigned)d, 64);
            if (lane >= d) {
#pragma unroll
                for (int c = 0; c < CDIM; ++c) bl[c] = fmaf(A, Bp[c], bl[c]);
                A *= Ap;
            }
        }

        // exclusive within wave (shift by one; lane 0 = identity)
        float Ae = __shfl_up(A, 1u, 64);
        float Be[CDIM];
#pragma unroll
        for (int c = 0; c < CDIM; ++c) Be[c] = __shfl_up(bl[c], 1u, 64);
        if (lane == 0) {
            Ae = 1.0f;
#pragma unroll
            for (int c = 0; c < CDIM; ++c) Be[c] = 0.0f;
        }

        // wave partials -> LDS, then compose prefix of earlier waves
        if (lane == 63) {
            sA[wid] = A;
#pragma unroll
            for (int c = 0; c < CDIM; ++c) sB[wid][c] = bl[c];
        }
        __syncthreads();

        float PB[CDIM];                    // (prefix of waves < wid)(0)
#pragma unroll
        for (int c = 0; c < CDIM; ++c) PB[c] = 0.0f;
        for (int w = 0; w < wid; ++w) {    // <= 7 iterations, LDS broadcasts
            const float Aw = sA[w];
#pragma unroll
            for (int c = 0; c < CDIM; ++c) PB[c] = fmaf(Aw, PB[c], sB[w][c]);
        }

        // ---- pass 2: exact EWMA from scanned start + inline screen ----
        if (act) {
            float y[CDIM];
#pragma unroll
            for (int c = 0; c < CDIM; ++c) y[c] = fmaf(Ae, PB[c], Be[c]);

#pragma unroll
            for (int k = 0; k < NT2; ++k) {
#pragma unroll
                for (int j = 0; j < 2; ++j) {
                    float s2 = 0.0f;
#pragma unroll
                    for (int c = 0; c < CDIM; ++c) {
                        y[c] = 0.5f * (f2elem(buf[k][c], j) + y[c]);
                        s2 = fmaf(y[c], y[c], s2);
                    }
                    if (s2 * wmax2 >= rhs2) {      // Cauchy-Schwarz screen
                        const int i = atomicAdd(&cnt, 1);
                        if (i < CAP) {
                            ct[i] = tstart + 2 * k + j;
#pragma unroll
                            for (int c = 0; c < CDIM; ++c) cy[i][c] = y[c];
                        } else {
                            ovf = 1;       // benign race: all writers store 1
                        }
                    }
                }
            }
        }
    }
    __syncthreads();

    // ---- phase 3: exact per-neuron check of LDS candidates ----
    if (!trivial) {
        const int n = cnt < CAP ? cnt : CAP;
        bool myhit = false;
        for (int i = 0; i < n; ++i) {
            const int t = ct[i];
            float yv[CDIM];
#pragma unroll
            for (int c = 0; c < CDIM; ++c) yv[c] = cy[i][c];   // LDS broadcast
            const float factor = 1.0f - exp2f(-(float)(t + 1));
#pragma unroll
            for (int j = 0; j < 2; ++j) {
                const float4 w0 = wv[2 * j], w1 = wv[2 * j + 1];
                const float a = w0.x * yv[0] + w0.y * yv[1] + w0.z * yv[2] + w0.w * yv[3] +
                                w1.x * yv[4] + w1.y * yv[5] + w1.z * yv[6] + w1.w * yv[7];
                const float v = a + (f2elem(bn2, j) + f2elem(br2, j)) * factor;
                myhit = myhit || (v >= VTHR);
            }
        }
        if (myhit) hit = 1;                // benign race: all writers store 1
    }
    __syncthreads();

    const bool spike = trivial || (ovf != 0) || (hit != 0);

    if (!spike) {
        // provably no spikes in this batch: counts are exactly zero
        reinterpret_cast<float2*>(out + (size_t)b * RDIM)[tid] =
            make_float2(0.0f, 0.0f);
        return;
    }

    // ---- phase 4 (rare): exact full simulation of this batch ----
    float w[2][CDIM], bias[2], v[2], cntv[2];
#pragma unroll
    for (int j = 0; j < 2; ++j) {
#pragma unroll
        for (int c = 0; c < 4; ++c) {
            w[j][c]     = f4elem(wv[2 * j], c);
            w[j][4 + c] = f4elem(wv[2 * j + 1], c);
        }
        bias[j] = f2elem(bn2, j) + f2elem(br2, j);
        v[j] = 0.0f;
        cntv[j] = 0.0f;
    }
    if (tid < 16) wmask[0][tid] = 0ULL;
    __syncthreads();

    const float* xbt = x + (size_t)b * (CDIM * TT);

    for (int t = 0; t < TT; ++t) {
        const int p = t & 1, q = p ^ 1;
        float xv[CDIM];
#pragma unroll
        for (int c = 0; c < CDIM; ++c) xv[c] = xbt[c * TT + t];

        float I[2];
#pragma unroll
        for (int j = 0; j < 2; ++j) {
            float a = bias[j];
#pragma unroll
            for (int c = 0; c < CDIM; ++c) a = fmaf(xv[c], w[j][c], a);
            I[j] = a;
        }
        // sparse recurrent input from previous step's spikes
        // bit l of wmask[p][W] (W = wid'*2+j') is neuron rp = 128*(W>>1)+2*l+(W&1)
        for (int W = 0; W < 16; ++W) {
            unsigned long long mm = wmask[p][W];
            while (mm) {
                const int l = __ffsll(mm) - 1;
                mm &= mm - 1;
                const int rp = 128 * (W >> 1) + 2 * l + (W & 1);
#pragma unroll
                for (int j = 0; j < 2; ++j)
                    I[j] += Wrec[(size_t)(r0 + j) * RDIM + rp];
            }
        }
        unsigned long long bmv[2];
#pragma unroll
        for (int j = 0; j < 2; ++j) {
            float vv = v[j] + (I[j] - v[j]) * 0.5f;
            const bool sp = (vv - 1.0f) >= 0.0f;
            cntv[j] += sp ? 1.0f : 0.0f;
            v[j] = sp ? 0.0f : vv;
            bmv[j] = __ballot(sp);
        }
        if (lane == 0) {
#pragma unroll
            for (int j = 0; j < 2; ++j) wmask[q][wid * 2 + j] = bmv[j];
        }
        __syncthreads();
    }
#pragma unroll
    for (int j = 0; j < 2; ++j) out[(size_t)b * RDIM + r0 + j] = cntv[j];
}

// ---------------------------------------------------------------------------
extern "C" void kernel_launch(void* const* d_in, const int* in_sizes, int n_in,
                              void* d_out, int out_size, void* d_ws, size_t ws_size,
                              hipStream_t stream) {
    const float* x    = (const float*)d_in[0];
    const float* Win  = (const float*)d_in[1];
    const float* bin  = (const float*)d_in[2];
    const float* Wrec = (const float*)d_in[3];
    const float* brec = (const float*)d_in[4];
    float* out = (float*)d_out;
    (void)d_ws; (void)ws_size;

    hipLaunchKernelGGL(snn_all, dim3(BATCH), dim3(NTH), 0, stream,
                       x, Win, bin, Wrec, brec, out);
}